// Round 7
// baseline (4937.873 us; speedup 1.0000x reference)
//
#include <hip/hip_runtime.h>

// Problem constants
#define Tt 256

// ws layout in unsigned shorts (fp16 bit patterns / ints for flags):
//  flags : 512 ints, 4B stride (packed; thread polls 2 via one 8B load)   [first 2KB of 32KB region]
//  h0 [2 parity][64 g][128 row][8]  fp16 frag-major     [256 KB]   (g = col>>3)
//  h1 same                                              [256 KB]
//  w0lo [128 hg][104 kg][16 n][8]  fp16, lo=(w-fp16(w))*1024, block-private frag-lane order
//  w1lo [128 hg][128 kg][16 n][8]
// total = 4,079,616 shorts = 8,159,232 B (proven-safe budget, unchanged from R5/R6)
#define FLAGS_SHORTS 16384
#define H0OFF  16384
#define H1OFF  (H0OFF + 2*64*128*8)
#define W0LOFF (H1OFF + 2*64*128*8)
#define W1LOFF (W0LOFF + 128*104*16*8)
#define HPAR   (64*128*8)            // u16 per parity plane = 65536

typedef _Float16 h8 __attribute__((ext_vector_type(8)));
typedef float    f4 __attribute__((ext_vector_type(4)));
typedef unsigned long long ull;
typedef unsigned short u16;

#define MFMA __builtin_amdgcn_mfma_f32_16x16x32_f16
#define LOSC (1.0f/1024.0f)

__device__ inline u16 h_bits(float f){ union{_Float16 h; u16 s;} u; u.h=(_Float16)f; return u.s; }
__device__ inline float bits_f(u16 s){ union{u16 s2; _Float16 h;} u; u.s2=s; return (float)u.h; }
__device__ inline float sigm(float x){ return 1.f/(1.f+expf(-x)); }

// Coherent 16B A-fragment load: two relaxed agent-scope 8B atomic loads.
// Agent scope => per-XCD-L2 bypass, served by IF$ (proven R2..R6).
// Frag-major h layout keeps these coalesced (16 fm-lanes x contiguous 16B).
__device__ inline h8 ldH(const u16* p){
    union{ ull u[2]; h8 v; } t;
    t.u[0]=__hip_atomic_load((const ull*)p,    __ATOMIC_RELAXED, __HIP_MEMORY_SCOPE_AGENT);
    t.u[1]=__hip_atomic_load((const ull*)(p+4),__ATOMIC_RELAXED, __HIP_MEMORY_SCOPE_AGENT);
    return t.v;
}

// ---------------- pre-pack W lo-planes (fp16, x1024) block-private frag-lane order ----------------
// identical to R6. one thread per (hg,kg,n) entry writing 8 u16.
__global__ __launch_bounds__(256) void prepack(const float* __restrict__ W0,
                                               const float* __restrict__ W1,
                                               u16* __restrict__ ws) {
    int idx = blockIdx.x * 256 + threadIdx.x;
    const int NW0 = 128 * 104 * 16;
    if (idx < NW0) {
        int hg  = idx / (104 * 16);
        int rem = idx - hg * (104 * 16);
        int kg = rem >> 4, n = rem & 15;
        int col = ((n >> 2) << 9) + (hg << 2) + (n & 3);
        u16 t[8];
#pragma unroll
        for (int j = 0; j < 8; j++) {
            int k = kg * 8 + j;
            float w = 0.f;
            if (k < 300) w = W0[k * 2048 + col];
            else if (k >= 320) w = W0[(k - 20) * 2048 + col];
            _Float16 wh = (_Float16)w;
            t[j] = h_bits((w - (float)wh) * 1024.0f);
        }
#pragma unroll
        for (int j = 0; j < 8; j++) ws[W0LOFF + (size_t)idx * 8 + j] = t[j];
    } else {
        int i2 = idx - NW0;
        if (i2 < 128 * 128 * 16) {
            int hg  = i2 >> 11;
            int rem = i2 & 2047;
            int kg = rem >> 4, n = rem & 15;
            int col = ((n >> 2) << 9) + (hg << 2) + (n & 3);
            u16 t[8];
#pragma unroll
            for (int j = 0; j < 8; j++) {
                float w = W1[(kg * 8 + j) * 2048 + col];
                _Float16 wh = (_Float16)w;
                t[j] = h_bits((w - (float)wh) * 1024.0f);
            }
#pragma unroll
            for (int j = 0; j < 8; j++) ws[W1LOFF + (size_t)i2 * 8 + j] = t[j];
        }
    }
}

// Fence-free split barrier (proven R2..R6), now 512 packed 4B flags.
// Initial ws poison (0xAAAAAAAA = negative int) reads < target, so no init needed.
__device__ inline void barrier_arrive(int* __restrict__ flags, int tid, int bid, int target) {
    __builtin_amdgcn_s_waitcnt(0);
    __syncthreads();
    if (tid == 0)
        __hip_atomic_store(flags + bid, target, __ATOMIC_RELAXED, __HIP_MEMORY_SCOPE_AGENT);
}
__device__ inline void barrier_wait(int* __restrict__ flags, int tid, int target) {
    for (;;) {
        ull v = __hip_atomic_load((const ull*)(flags + tid * 2), __ATOMIC_RELAXED, __HIP_MEMORY_SCOPE_AGENT);
        if ((int)(unsigned)v >= target && (int)(unsigned)(v >> 32) >= target) break;
        __builtin_amdgcn_s_sleep(1);
    }
    __syncthreads();
}

struct X2 { f4 h, l; };

// ---------------- persistent cooperative LSTM kernel ----------------
// grid 512 x 256 (2 blocks/CU): bid = inner*2 + lyr.
//   lyr  = bid&1      : 0 -> layer-0 duties, 1 -> layer-1 duties (the two GEMMs of a
//                       phase are data-independent — both read only phase p-1 outputs)
//   inner= bid>>1     : bq = inner>>7 (64-row batch half), hg = inner&127 (4 h-cols)
// Per-block GEMM code is R6's layer-specific half, verbatim; h/W layouts unchanged.
__global__ __launch_bounds__(256, 1) void lstm_coop(
    const int* __restrict__ x, const float* __restrict__ emb,
    const float* __restrict__ W0, const float* __restrict__ b0,
    const float* __restrict__ W1, const float* __restrict__ b1,
    const float* __restrict__ Wd, const float* __restrict__ bd,
    float* __restrict__ out, u16* __restrict__ ws) {

    const int tid  = threadIdx.x;
    const int lane = tid & 63;
    const int wave = tid >> 6;        // 0..3 : m-tile (16 rows each)
    const int quad = lane >> 4;       // 0..3 : k-chunk of 8 in frags
    const int fm   = lane & 15;       // A: m, B: n, C/D: col
    const int bid  = blockIdx.x;
    const int lyr  = bid & 1;
    const int inner= bid >> 1;
    const int bq   = inner >> 7;
    const int hg   = inner & 127;

    __shared__ u16   whi[128 * 16 * 8];   // 32,768 B (lyr0 uses first 104*16*8)
    __shared__ float csm[64 * 17];        //  4,352 B  (37,120 B total -> 4 blocks/CU allowed)

    int* flags = (int*)ws;
    const u16* w0lo = ws + W0LOFF + (size_t)hg * 104 * 16 * 8;   // block-private slice
    const u16* w1lo = ws + W1LOFF + (size_t)hg * 128 * 16 * 8;

    // --- fill LDS hi-plane (fp16) of this block's layer & 16 weight columns, frag layout [kg][n][8] ---
    if (lyr == 0) {
        for (int i = tid; i < 104 * 16 * 8; i += 256) {
            int kg = i >> 7; int rem = i & 127; int n = rem >> 3; int j = rem & 7;
            int k = kg * 8 + j;
            int col = ((n >> 2) << 9) + (hg << 2) + (n & 3);
            float w = 0.f;
            if (k < 300) w = W0[k * 2048 + col];
            else if (k >= 320) w = W0[(k - 20) * 2048 + col];
            whi[i] = h_bits(w);
        }
    } else {
        for (int i = tid; i < 128 * 16 * 8; i += 256) {
            int kg = i >> 7; int rem = i & 127; int n = rem >> 3; int j = rem & 7;
            int k = kg * 8 + j;
            int col = ((n >> 2) << 9) + (hg << 2) + (n & 3);
            whi[i] = h_bits(W1[k * 2048 + col]);
        }
    }

    // h addressing (frag-major, unchanged): plane u16 index = hbase + row*8 + c
    const int hbase = ((hg >> 1) * 128) * 8 + (hg & 1) * 4;

    // --- zero-init own slice: lyr0 -> h0 parity 0 ; lyr1 -> h1 parity 1 ---
    if (tid < 128) {
        int row = bq * 64 + (tid >> 1);
        int c = (tid & 1) << 1;
        unsigned int* pz = (unsigned int*)(ws + (lyr ? H1OFF + 1 * HPAR : H0OFF + 0 * HPAR)
                                           + hbase + row * 8 + c);
        __hip_atomic_store(pz, 0u, __ATOMIC_RELAXED, __HIP_MEMORY_SCOPE_AGENT);
    }

    const int arow   = bq * 64 + wave * 16 + fm;  // A-frag row (batch index)
    const int actm   = tid >> 2;
    const int acthc  = tid & 3;
    const int actrow = bq * 64 + actm;
    const int actcol = (hg << 2) + acthc;

    // biases: only this block's layer
    const float bi = lyr ? b1[actcol]        : b0[actcol];
    const float bj = lyr ? b1[512 + actcol]  : b0[512 + actcol];
    const float bf = lyr ? b1[1024 + actcol] : b0[1024 + actcol];
    const float bo = lyr ? b1[1536 + actcol] : b0[1536 + actcol];

    float cs = 0.f;     // c0 (lyr0) or c1 (lyr1) persistent slice

    // x-part GEMM of layer 0 for timestep pp (kt 0..9), recurrence-independent;
    // lyr0 only; runs inside the barrier arrive->wait window.
    auto xgemm = [&](int pp) -> X2 {
        X2 a; a.h = (f4){0,0,0,0}; a.l = a.h;
        int xi = x[arow * Tt + pp];
        xi = (xi < 0) ? 0 : ((xi >= 50000) ? 49999 : xi);
        const float* embrow = emb + (size_t)xi * 300;
#pragma unroll
        for (int kt = 0; kt < 10; kt++) {
            int kbase = kt * 32 + quad * 8;
            h8 af;
            if (kt < 9) {
                f4 u0 = *(const f4*)(embrow + kbase);
                f4 u1 = *(const f4*)(embrow + kbase + 4);
#pragma unroll
                for (int e = 0; e < 4; e++) { af[e] = (_Float16)u0[e]; af[4+e] = (_Float16)u1[e]; }
            } else {
#pragma unroll
                for (int e = 0; e < 8; e++) { int kk = kbase + e; af[e] = (_Float16)((kk < 300) ? embrow[kk] : 0.f); }
            }
            int kg = kt * 4 + quad;
            a.h = MFMA(af, *(const h8*)&whi[(kg * 16 + fm) * 8], a.h, 0,0,0);
            a.l = MFMA(af, *(const h8*)(w0lo + (kg * 16 + fm) * 8), a.l, 0,0,0);
        }
        return a;
    };

    X2 accx;
    barrier_arrive(flags, tid, bid, 1);
    if (lyr == 0) accx = xgemm(0);
    barrier_wait(flags, tid, 1);

    for (int p = 0; p <= Tt; ++p) {
        const int par = p & 1, wpar = 1 - par;

        if (lyr == 1) {
            if (p >= 1) {   // ---- layer 1 for t=p-1 : g1 = [h0(p-1) | h1(p-2)] @ W1 ----
                f4 aH = (f4){0,0,0,0}, aL = aH;
                const u16* h0p = ws + H0OFF + par * HPAR + arow * 8;
                const u16* h1p = ws + H1OFF + par * HPAR + arow * 8;
#pragma unroll 8
                for (int kt = 0; kt < 32; kt++) {
                    h8 af = (kt < 16) ? ldH(h0p + (kt * 4 + quad) * 1024)
                                      : ldH(h1p + ((kt - 16) * 4 + quad) * 1024);
                    int kg = kt * 4 + quad;
                    aH = MFMA(af, *(const h8*)&whi[(kg * 16 + fm) * 8], aH, 0,0,0);
                    aL = MFMA(af, *(const h8*)(w1lo + (kg * 16 + fm) * 8), aL, 0,0,0);
                }
#pragma unroll
                for (int r = 0; r < 4; r++)
                    csm[(wave * 16 + quad * 4 + r) * 17 + fm] = aH[r] + aL[r] * LOSC;
                __syncthreads();
                {
                    float gi = csm[actm * 17 + acthc]      + bi;
                    float gj = csm[actm * 17 + 4 + acthc]  + bj;
                    float gf = csm[actm * 17 + 8 + acthc]  + bf;
                    float go = csm[actm * 17 + 12 + acthc] + bo;
                    cs = cs * sigm(gf + 1.f) + sigm(gi) * tanhf(gj);
                    float h = tanhf(cs) * sigm(go);
                    u16 hb = h_bits(h);
                    unsigned int pk = (unsigned int)hb | (((unsigned int)(u16)__shfl_xor((int)hb, 1, 64)) << 16);
                    if (!(acthc & 1)) {
                        unsigned int* d = (unsigned int*)(ws + H1OFF + wpar * HPAR + hbase + actrow * 8 + acthc);
                        __hip_atomic_store(d, pk, __ATOMIC_RELAXED, __HIP_MEMORY_SCOPE_AGENT);
                    }
                }
            }
        } else {
            if (p < Tt) {   // ---- layer 0 h-part for t=p (x-part already in accx) ----
                f4 aH = accx.h, aL = accx.l;
                const u16* h0p = ws + H0OFF + par * HPAR + arow * 8;
#pragma unroll 8
                for (int kt = 10; kt < 26; kt++) {
                    h8 af = ldH(h0p + (kt * 4 + quad - 40) * 1024);
                    int kg = kt * 4 + quad;
                    aH = MFMA(af, *(const h8*)&whi[(kg * 16 + fm) * 8], aH, 0,0,0);
                    aL = MFMA(af, *(const h8*)(w0lo + (kg * 16 + fm) * 8), aL, 0,0,0);
                }
#pragma unroll
                for (int r = 0; r < 4; r++)
                    csm[(wave * 16 + quad * 4 + r) * 17 + fm] = aH[r] + aL[r] * LOSC;
                __syncthreads();
                {
                    float gi = csm[actm * 17 + acthc]      + bi;
                    float gj = csm[actm * 17 + 4 + acthc]  + bj;
                    float gf = csm[actm * 17 + 8 + acthc]  + bf;
                    float go = csm[actm * 17 + 12 + acthc] + bo;
                    cs = cs * sigm(gf + 1.f) + sigm(gi) * tanhf(gj);
                    float h = tanhf(cs) * sigm(go);
                    u16 hb = h_bits(h);
                    unsigned int pk = (unsigned int)hb | (((unsigned int)(u16)__shfl_xor((int)hb, 1, 64)) << 16);
                    if (!(acthc & 1)) {
                        unsigned int* d = (unsigned int*)(ws + H0OFF + wpar * HPAR + hbase + actrow * 8 + acthc);
                        __hip_atomic_store(d, pk, __ATOMIC_RELAXED, __HIP_MEMORY_SCOPE_AGENT);
                    }
                }
            }
        }

        barrier_arrive(flags, tid, bid, p + 2);
        if (lyr == 0 && p + 1 < Tt) accx = xgemm(p + 1);
        barrier_wait(flags, tid, p + 2);
    }

    // ---- final logits: h1(T-1) lives in parity 1 (frag-major addressing) ----
    if (bid == 0) {
        int b = tid >> 1, jj = tid & 1;
        float sum = bd[jj];
        const u16* hh = ws + H1OFF + 1 * HPAR;
        for (int g = 0; g < 64; g++) {
#pragma unroll
            for (int j4 = 0; j4 < 8; j4 += 4) {
                ull u = __hip_atomic_load((const ull*)(hh + (g * 128 + b) * 8 + j4),
                                          __ATOMIC_RELAXED, __HIP_MEMORY_SCOPE_AGENT);
#pragma unroll
                for (int e = 0; e < 4; e++)
                    sum += bits_f((u16)(u >> (16 * e))) * Wd[(g * 8 + j4 + e) * 2 + jj];
            }
        }
        out[b * 2 + jj] = sum;
    }
}

extern "C" void kernel_launch(void* const* d_in, const int* in_sizes, int n_in,
                              void* d_out, int out_size, void* d_ws, size_t ws_size,
                              hipStream_t stream) {
    const int*   x   = (const int*)d_in[0];
    const float* emb = (const float*)d_in[1];
    const float* W0  = (const float*)d_in[2];
    const float* b0  = (const float*)d_in[3];
    const float* W1  = (const float*)d_in[4];
    const float* b1  = (const float*)d_in[5];
    const float* Wd  = (const float*)d_in[6];
    const float* bd  = (const float*)d_in[7];
    float* out = (float*)d_out;
    u16* ws = (u16*)d_ws;

    hipLaunchKernelGGL(prepack, dim3(1856), dim3(256), 0, stream, W0, W1, ws);

    void* args[] = { (void*)&x, (void*)&emb, (void*)&W0, (void*)&b0, (void*)&W1,
                     (void*)&b1, (void*)&Wd, (void*)&bd, (void*)&out, (void*)&ws };
    hipLaunchCooperativeKernel((void*)lstm_coop, dim3(512), dim3(256), args, 0, stream);
}

// Round 9
// 4235.401 us; speedup vs baseline: 1.1659x; 1.1659x over previous
//
#include <hip/hip_runtime.h>

// Problem constants
#define Tt 256

// ws layout in unsigned shorts (fp16 bit patterns / ints for flags):
//  flags : ints [0..256) arrival flags (4B packed)      [first 1KB of 32KB region]
//  h0 [2 parity][64 g][128 row][8]  fp16 frag-major     [256 KB]   (g = col>>3)
//  h1 same                                              [256 KB]
//  w0lo [64 cg][104 kg][32 n][8]  fp16, lo=(w-fp16(w))*1024, block-private frag-lane order
//  w1lo [64 cg][128 kg][32 n][8]
// total = 4,079,616 shorts = 8,159,232 B (byte-identical to the R5..R7 proven budget)
#define FLAGS_SHORTS 16384
#define H0OFF  16384
#define H1OFF  (H0OFF + 2*64*128*8)
#define W0LOFF (H1OFF + 2*64*128*8)
#define W1LOFF (W0LOFF + 64*104*32*8)
#define HPAR   (64*128*8)            // u16 per parity plane = 65536

typedef _Float16 h8 __attribute__((ext_vector_type(8)));
typedef float    f4 __attribute__((ext_vector_type(4)));
typedef unsigned long long ull;
typedef unsigned short u16;

#define MFMA __builtin_amdgcn_mfma_f32_16x16x32_f16
#define LOSC (1.0f/1024.0f)

__device__ inline u16 h_bits(float f){ union{_Float16 h; u16 s;} u; u.h=(_Float16)f; return u.s; }
__device__ inline float bits_f(u16 s){ union{u16 s2; _Float16 h;} u; u.s2=s; return (float)u.h; }
__device__ inline float sigm(float x){ return 1.f/(1.f+expf(-x)); }

// Coherent 16B A-fragment load: two relaxed agent-scope 8B atomic loads (IF$-served, proven R2..R7).
__device__ inline h8 ldH(const u16* p){
    union{ ull u[2]; h8 v; } t;
    t.u[0]=__hip_atomic_load((const ull*)p,    __ATOMIC_RELAXED, __HIP_MEMORY_SCOPE_AGENT);
    t.u[1]=__hip_atomic_load((const ull*)(p+4),__ATOMIC_RELAXED, __HIP_MEMORY_SCOPE_AGENT);
    return t.v;
}

// ---------------- pre-pack W lo-planes (fp16, x1024), [cg][kg][n 0..32)[8] ----------------
__global__ __launch_bounds__(256) void prepack(const float* __restrict__ W0,
                                               const float* __restrict__ W1,
                                               u16* __restrict__ ws) {
    int idx = blockIdx.x * 256 + threadIdx.x;
    const int NW0 = 64 * 104 * 32;
    if (idx < NW0) {
        int cg  = idx / (104 * 32);
        int rem = idx - cg * (104 * 32);
        int kg = rem >> 5, n = rem & 31;
        int col = ((n >> 3) << 9) + (cg << 3) + (n & 7);
        u16 t[8];
#pragma unroll
        for (int j = 0; j < 8; j++) {
            int k = kg * 8 + j;
            float w = 0.f;
            if (k < 300) w = W0[k * 2048 + col];
            else if (k >= 320) w = W0[(k - 20) * 2048 + col];
            _Float16 wh = (_Float16)w;
            t[j] = h_bits((w - (float)wh) * 1024.0f);
        }
#pragma unroll
        for (int j = 0; j < 8; j++) ws[W0LOFF + (size_t)idx * 8 + j] = t[j];
    } else {
        int i2 = idx - NW0;
        if (i2 < 64 * 128 * 32) {
            int cg  = i2 >> 12;           // / (128*32)
            int rem = i2 & 4095;
            int kg = rem >> 5, n = rem & 31;
            int col = ((n >> 3) << 9) + (cg << 3) + (n & 7);
            u16 t[8];
#pragma unroll
            for (int j = 0; j < 8; j++) {
                float w = W1[(kg * 8 + j) * 2048 + col];
                _Float16 wh = (_Float16)w;
                t[j] = h_bits((w - (float)wh) * 1024.0f);
            }
#pragma unroll
            for (int j = 0; j < 8; j++) ws[W1LOFF + (size_t)i2 * 8 + j] = t[j];
        }
    }
}

// Fence-free split barrier — EXACT R7-proven structure (all threads poll packed flags).
// 256 blocks: thread tid polls flags[tid]. Initial poison (0xAAAAAAAA<0) needs no init.
__device__ inline void barrier_arrive(int* __restrict__ flags, int tid, int bid, int target) {
    __builtin_amdgcn_s_waitcnt(0);
    __syncthreads();
    if (tid == 0)
        __hip_atomic_store(flags + bid, target, __ATOMIC_RELAXED, __HIP_MEMORY_SCOPE_AGENT);
}
__device__ inline void barrier_wait(int* __restrict__ flags, int tid, int target) {
    while (__hip_atomic_load(flags + tid, __ATOMIC_RELAXED, __HIP_MEMORY_SCOPE_AGENT) < target)
        __builtin_amdgcn_s_sleep(1);
    __syncthreads();
}

struct X4 { f4 h0, l0, h1, l1; };

// ---------------- persistent cooperative LSTM kernel ----------------
// grid 256 x 256 (1 block/CU): bid = inner*2 + lyr.
//   lyr = bid&1 : 0 -> layer-0 duties, 1 -> layer-1 duties (R7 split, proven)
//   inner = bid>>1 in [0,128): bq = inner>>6 (64-row batch half), cg = inner&63 (8 h-cols
//   -> 32 gate-cols). Each wave loads ONE A-frag per kt and reuses it for BOTH n-tiles,
//   halving the per-h-element consumer count (24 MB/phase coherent vs R7's 48).
__global__ __launch_bounds__(256, 1) void lstm_coop(
    const int* __restrict__ x, const float* __restrict__ emb,
    const float* __restrict__ W0, const float* __restrict__ b0,
    const float* __restrict__ W1, const float* __restrict__ b1,
    const float* __restrict__ Wd, const float* __restrict__ bd,
    float* __restrict__ out, u16* __restrict__ ws) {

    const int tid  = threadIdx.x;
    const int lane = tid & 63;
    const int wave = tid >> 6;        // 0..3 : m-tile (16 rows each)
    const int quad = lane >> 4;       // 0..3 : k-chunk of 8 in frags
    const int fm   = lane & 15;       // A: m, B: n, C/D: col
    const int bid  = blockIdx.x;
    const int lyr  = bid & 1;
    const int inner= bid >> 1;
    const int bq   = inner >> 6;
    const int cg   = inner & 63;

    __shared__ u16   whi[128 * 32 * 8];   // 65,536 B (lyr0 uses first 104*32*8)
    __shared__ float csm[64 * 33];        //  8,448 B  (73,984 B total -> 2 blocks/CU validates)

    int* flags = (int*)ws;
    const u16* w0lo = ws + W0LOFF + (size_t)cg * 104 * 32 * 8;   // block-private slice
    const u16* w1lo = ws + W1LOFF + (size_t)cg * 128 * 32 * 8;

    // --- fill LDS hi-plane (fp16) of this block's layer & 32 gate columns, layout [kg][n][8] ---
    if (lyr == 0) {
        for (int i = tid; i < 104 * 32 * 8; i += 256) {
            int kg = i >> 8; int rem = i & 255; int n = rem >> 3; int j = rem & 7;
            int k = kg * 8 + j;
            int col = ((n >> 3) << 9) + (cg << 3) + (n & 7);
            float w = 0.f;
            if (k < 300) w = W0[k * 2048 + col];
            else if (k >= 320) w = W0[(k - 20) * 2048 + col];
            whi[i] = h_bits(w);
        }
    } else {
        for (int i = tid; i < 128 * 32 * 8; i += 256) {
            int kg = i >> 8; int rem = i & 255; int n = rem >> 3; int j = rem & 7;
            int k = kg * 8 + j;
            int col = ((n >> 3) << 9) + (cg << 3) + (n & 7);
            whi[i] = h_bits(W1[k * 2048 + col]);
        }
    }

    // h addressing (frag-major, unchanged layout): plane u16 index = cg*1024 + row*8 + c, c in [0,8)
    // --- zero-init own slice: lyr0 -> h0 parity 0 ; lyr1 -> h1 parity 1 (64 rows x 8 cols) ---
    {
        int row = bq * 64 + (tid >> 2);
        int c = (tid & 3) << 1;
        unsigned int* pz = (unsigned int*)(ws + (lyr ? H1OFF + 1 * HPAR : H0OFF + 0 * HPAR)
                                           + cg * 1024 + row * 8 + c);
        __hip_atomic_store(pz, 0u, __ATOMIC_RELAXED, __HIP_MEMORY_SCOPE_AGENT);
    }

    const int arow = bq * 64 + wave * 16 + fm;   // A-frag row (batch index)
    // act cell: 2 cells per thread: (row m, h-cols hc and hc+4)
    const int actm   = tid >> 2;
    const int acthc  = tid & 3;
    const int actrow = bq * 64 + actm;
    const int ca = (cg << 3) + acthc;        // global h-col of cell A
    const int cb = ca + 4;                   // cell B

    const float biA = lyr ? b1[ca]        : b0[ca];
    const float bjA = lyr ? b1[512 + ca]  : b0[512 + ca];
    const float bfA = lyr ? b1[1024 + ca] : b0[1024 + ca];
    const float boA = lyr ? b1[1536 + ca] : b0[1536 + ca];
    const float biB = lyr ? b1[cb]        : b0[cb];
    const float bjB = lyr ? b1[512 + cb]  : b0[512 + cb];
    const float bfB = lyr ? b1[1024 + cb] : b0[1024 + cb];
    const float boB = lyr ? b1[1536 + cb] : b0[1536 + cb];

    float csA = 0.f, csB = 0.f;

    // x-part GEMM of layer 0 for timestep pp (kt 0..9, both n-tiles); lyr0 only,
    // runs inside the barrier arrive->wait window.
    auto xgemm = [&](int pp) -> X4 {
        X4 a; a.h0 = (f4){0,0,0,0}; a.l0 = a.h0; a.h1 = a.h0; a.l1 = a.h0;
        int xi = x[arow * Tt + pp];
        xi = (xi < 0) ? 0 : ((xi >= 50000) ? 49999 : xi);
        const float* embrow = emb + (size_t)xi * 300;
#pragma unroll
        for (int kt = 0; kt < 10; kt++) {
            int kbase = kt * 32 + quad * 8;
            h8 af;
            if (kt < 9) {
                f4 u0 = *(const f4*)(embrow + kbase);
                f4 u1 = *(const f4*)(embrow + kbase + 4);
#pragma unroll
                for (int e = 0; e < 4; e++) { af[e] = (_Float16)u0[e]; af[4+e] = (_Float16)u1[e]; }
            } else {
#pragma unroll
                for (int e = 0; e < 8; e++) { int kk = kbase + e; af[e] = (_Float16)((kk < 300) ? embrow[kk] : 0.f); }
            }
            int kb = (kt * 4 + quad) * 32;
            a.h0 = MFMA(af, *(const h8*)&whi[(kb + fm) * 8],        a.h0, 0,0,0);
            a.l0 = MFMA(af, *(const h8*)(w0lo + (kb + fm) * 8),      a.l0, 0,0,0);
            a.h1 = MFMA(af, *(const h8*)&whi[(kb + 16 + fm) * 8],   a.h1, 0,0,0);
            a.l1 = MFMA(af, *(const h8*)(w0lo + (kb + 16 + fm) * 8), a.l1, 0,0,0);
        }
        return a;
    };

    X4 accx;
    barrier_arrive(flags, tid, bid, 1);
    if (lyr == 0) accx = xgemm(0);
    barrier_wait(flags, tid, 1);

    for (int p = 0; p <= Tt; ++p) {
        const int par = p & 1, wpar = 1 - par;

        if (lyr == 1) {
            if (p >= 1) {   // ---- layer 1 for t=p-1 : g1 = [h0(p-1) | h1(p-2)] @ W1 ----
                f4 aH0 = (f4){0,0,0,0}, aL0 = aH0, aH1 = aH0, aL1 = aH0;
                const u16* h0p = ws + H0OFF + par * HPAR + arow * 8;
                const u16* h1p = ws + H1OFF + par * HPAR + arow * 8;
#pragma unroll 8
                for (int kt = 0; kt < 32; kt++) {
                    h8 af = (kt < 16) ? ldH(h0p + (kt * 4 + quad) * 1024)
                                      : ldH(h1p + ((kt - 16) * 4 + quad) * 1024);
                    int kb = (kt * 4 + quad) * 32;
                    aH0 = MFMA(af, *(const h8*)&whi[(kb + fm) * 8],        aH0, 0,0,0);
                    aL0 = MFMA(af, *(const h8*)(w1lo + (kb + fm) * 8),      aL0, 0,0,0);
                    aH1 = MFMA(af, *(const h8*)&whi[(kb + 16 + fm) * 8],   aH1, 0,0,0);
                    aL1 = MFMA(af, *(const h8*)(w1lo + (kb + 16 + fm) * 8), aL1, 0,0,0);
                }
#pragma unroll
                for (int r = 0; r < 4; r++) {
                    csm[(wave * 16 + quad * 4 + r) * 33 + fm]      = aH0[r] + aL0[r] * LOSC;
                    csm[(wave * 16 + quad * 4 + r) * 33 + 16 + fm] = aH1[r] + aL1[r] * LOSC;
                }
                __syncthreads();
                {   // gates: in-block col = gate*8 + hc
                    float giA = csm[actm * 33 + acthc]           + biA;
                    float gjA = csm[actm * 33 + 8 + acthc]       + bjA;
                    float gfA = csm[actm * 33 + 16 + acthc]      + bfA;
                    float goA = csm[actm * 33 + 24 + acthc]      + boA;
                    float giB = csm[actm * 33 + 4 + acthc]       + biB;
                    float gjB = csm[actm * 33 + 12 + acthc]      + bjB;
                    float gfB = csm[actm * 33 + 20 + acthc]      + bfB;
                    float goB = csm[actm * 33 + 28 + acthc]      + boB;
                    csA = csA * sigm(gfA + 1.f) + sigm(giA) * tanhf(gjA);
                    csB = csB * sigm(gfB + 1.f) + sigm(giB) * tanhf(gjB);
                    float hA = tanhf(csA) * sigm(goA);
                    float hB = tanhf(csB) * sigm(goB);
                    u16 ha = h_bits(hA), hb = h_bits(hB);
                    unsigned int pa = (unsigned int)ha | (((unsigned int)(u16)__shfl_xor((int)ha, 1, 64)) << 16);
                    unsigned int pb = (unsigned int)hb | (((unsigned int)(u16)__shfl_xor((int)hb, 1, 64)) << 16);
                    if (!(acthc & 1)) {
                        u16* base = ws + H1OFF + wpar * HPAR + cg * 1024 + actrow * 8;
                        __hip_atomic_store((unsigned int*)(base + acthc),     pa, __ATOMIC_RELAXED, __HIP_MEMORY_SCOPE_AGENT);
                        __hip_atomic_store((unsigned int*)(base + 4 + acthc), pb, __ATOMIC_RELAXED, __HIP_MEMORY_SCOPE_AGENT);
                    }
                }
            }
        } else {
            if (p < Tt) {   // ---- layer 0 h-part for t=p (x-part already in accx) ----
                f4 aH0 = accx.h0, aL0 = accx.l0, aH1 = accx.h1, aL1 = accx.l1;
                const u16* h0p = ws + H0OFF + par * HPAR + arow * 8;
#pragma unroll 8
                for (int kt = 10; kt < 26; kt++) {
                    h8 af = ldH(h0p + (kt * 4 + quad - 40) * 1024);
                    int kb = (kt * 4 + quad) * 32;
                    aH0 = MFMA(af, *(const h8*)&whi[(kb + fm) * 8],        aH0, 0,0,0);
                    aL0 = MFMA(af, *(const h8*)(w0lo + (kb + fm) * 8),      aL0, 0,0,0);
                    aH1 = MFMA(af, *(const h8*)&whi[(kb + 16 + fm) * 8],   aH1, 0,0,0);
                    aL1 = MFMA(af, *(const h8*)(w0lo + (kb + 16 + fm) * 8), aL1, 0,0,0);
                }
#pragma unroll
                for (int r = 0; r < 4; r++) {
                    csm[(wave * 16 + quad * 4 + r) * 33 + fm]      = aH0[r] + aL0[r] * LOSC;
                    csm[(wave * 16 + quad * 4 + r) * 33 + 16 + fm] = aH1[r] + aL1[r] * LOSC;
                }
                __syncthreads();
                {
                    float giA = csm[actm * 33 + acthc]           + biA;
                    float gjA = csm[actm * 33 + 8 + acthc]       + bjA;
                    float gfA = csm[actm * 33 + 16 + acthc]      + bfA;
                    float goA = csm[actm * 33 + 24 + acthc]      + boA;
                    float giB = csm[actm * 33 + 4 + acthc]       + biB;
                    float gjB = csm[actm * 33 + 12 + acthc]      + bjB;
                    float gfB = csm[actm * 33 + 20 + acthc]      + bfB;
                    float goB = csm[actm * 33 + 28 + acthc]      + boB;
                    csA = csA * sigm(gfA + 1.f) + sigm(giA) * tanhf(gjA);
                    csB = csB * sigm(gfB + 1.f) + sigm(giB) * tanhf(gjB);
                    float hA = tanhf(csA) * sigm(goA);
                    float hB = tanhf(csB) * sigm(goB);
                    u16 ha = h_bits(hA), hb = h_bits(hB);
                    unsigned int pa = (unsigned int)ha | (((unsigned int)(u16)__shfl_xor((int)ha, 1, 64)) << 16);
                    unsigned int pb = (unsigned int)hb | (((unsigned int)(u16)__shfl_xor((int)hb, 1, 64)) << 16);
                    if (!(acthc & 1)) {
                        u16* base = ws + H0OFF + wpar * HPAR + cg * 1024 + actrow * 8;
                        __hip_atomic_store((unsigned int*)(base + acthc),     pa, __ATOMIC_RELAXED, __HIP_MEMORY_SCOPE_AGENT);
                        __hip_atomic_store((unsigned int*)(base + 4 + acthc), pb, __ATOMIC_RELAXED, __HIP_MEMORY_SCOPE_AGENT);
                    }
                }
            }
        }

        barrier_arrive(flags, tid, bid, p + 2);
        if (lyr == 0 && p + 1 < Tt) accx = xgemm(p + 1);
        barrier_wait(flags, tid, p + 2);
    }

    // ---- final logits: h1(T-1) lives in parity 1 (frag-major addressing, unchanged) ----
    if (bid == 0) {
        int b = tid >> 1, jj = tid & 1;
        float sum = bd[jj];
        const u16* hh = ws + H1OFF + 1 * HPAR;
        for (int g = 0; g < 64; g++) {
#pragma unroll
            for (int j4 = 0; j4 < 8; j4 += 4) {
                ull u = __hip_atomic_load((const ull*)(hh + (g * 128 + b) * 8 + j4),
                                          __ATOMIC_RELAXED, __HIP_MEMORY_SCOPE_AGENT);
#pragma unroll
                for (int e = 0; e < 4; e++)
                    sum += bits_f((u16)(u >> (16 * e))) * Wd[(g * 8 + j4 + e) * 2 + jj];
            }
        }
        out[b * 2 + jj] = sum;
    }
}

extern "C" void kernel_launch(void* const* d_in, const int* in_sizes, int n_in,
                              void* d_out, int out_size, void* d_ws, size_t ws_size,
                              hipStream_t stream) {
    const int*   x   = (const int*)d_in[0];
    const float* emb = (const float*)d_in[1];
    const float* W0  = (const float*)d_in[2];
    const float* b0  = (const float*)d_in[3];
    const float* W1  = (const float*)d_in[4];
    const float* b1  = (const float*)d_in[5];
    const float* Wd  = (const float*)d_in[6];
    const float* bd  = (const float*)d_in[7];
    float* out = (float*)d_out;
    u16* ws = (u16*)d_ws;

    hipLaunchKernelGGL(prepack, dim3(1856), dim3(256), 0, stream, W0, W1, ws);

    void* args[] = { (void*)&x, (void*)&emb, (void*)&W0, (void*)&b0, (void*)&W1,
                     (void*)&b1, (void*)&Wd, (void*)&bd, (void*)&out, (void*)&ws };
    hipLaunchCooperativeKernel((void*)lstm_coop, dim3(256), dim3(256), args, 0, stream);
}